// Round 4
// baseline (689.108 us; speedup 1.0000x reference)
//
#include <hip/hip_runtime.h>
#include <math.h>

// (B,T,D,H,O) = (1024, 512, 64, 64, 32)
#define BB 1024
#define TT 512
#define OO 32
#define MM 4               // batch rows per block
#define NBLK (BB/MM)       // 256 blocks -> all 256 CUs
#define SS 8               // timesteps per slot (between barriers)
#define NSLOT 66           // L0 rec s=0..63, L1 rec s=2..65

typedef __attribute__((ext_vector_type(8))) short short8;   // 8 bf16
typedef __attribute__((ext_vector_type(4))) float f32x4;    // MFMA C/D

#define MFMA __builtin_amdgcn_mfma_f32_16x16x32_bf16
#define LOG2E 1.4426950408889634f
#define K2    2.8853900817779268f   /* 2*log2(e) */

// Raw barrier: waits own LDS ops then rendezvous (globals stay in flight)
#define BAR() asm volatile("s_waitcnt lgkmcnt(0)\n\ts_barrier" ::: "memory")

__device__ __forceinline__ float exp2f_(float x) {
#if __has_builtin(__builtin_amdgcn_exp2f)
    return __builtin_amdgcn_exp2f(x);
#else
    float r; asm("v_exp_f32 %0, %1" : "=v"(r) : "v"(x)); return r;
#endif
}

// fp32 -> bf16 RNE (one-time weight conversion)
__device__ __forceinline__ ushort f2bf(float f) {
    union { float f; unsigned u; } v; v.f = f;
    unsigned r = v.u + 0x7FFF + ((v.u >> 16) & 1);
    return (ushort)(r >> 16);
}
__device__ __forceinline__ float bf2f(ushort u) {
    union { unsigned u; float f; } v; v.u = ((unsigned)u) << 16; return v.f;
}
// pack two fp32 -> bf16x2 via v_perm (round-half-up)
__device__ __forceinline__ unsigned pkbf(float a, float b) {
    union { float f; unsigned u; } x, y; x.f = a; y.f = b;
    return __builtin_amdgcn_perm(y.u + 0x8000u, x.u + 0x8000u, 0x07060302u);
}
__device__ __forceinline__ short8 pack8(const float4& a, const float4& b) {
    union { unsigned u[4]; short8 s; } r;
    r.u[0] = pkbf(a.x, a.y); r.u[1] = pkbf(a.z, a.w);
    r.u[2] = pkbf(b.x, b.y); r.u[3] = pkbf(b.z, b.w);
    return r.s;
}

// ===========================================================================
// 8 symmetric hybrid waves / block (512 thr, 2 waves/SIMD for latency hiding).
//   wv 0-3: layer-0, batch row wv.   wv 4-7: layer-1, batch row wv-4 (lag 16).
// Each wave: full W_hh of its layer in regs (32 short8 = 128 VGPR); per step
// A = h(t-1) broadcast into all 16 M-rows (rows dup; MFMA row R depends only
// on A row R). Lane (q,l) uses acc[0] of tiles (g, c==q) -> unit 16q+l ->
// EXACTLY 1 cell/lane (8 trans/step, was 32). Chains pipelined: per c-block
// 4 first-K MFMA then 4 second-K. pre layout [tau][row][unit][4 gates] ->
// one ds_read_b128/step. h rings: row-XOR swizzle (byte^16*row).
// Coop (per slot, same waves): L0 wave computes pre0 tiles (g,c=row) for
// slot s+1 (x loads ISSUED before rec -> HBM latency hidden under 8 steps);
// L1 wave computes pre1 tiles for L1-slot s-1 from h0 ring (reads issued
// before rec). Bias added in rec (coop C = 0). 1 barrier/slot (66 total).
// Ring disjointness per slot s:
//   pre0: L0 rec reads buf s&1,      L0 coop writes buf (s+1)&1
//   pre1: L1 rec reads buf (s-2)&1,  L1 coop writes buf (s-1)&1
//   h0  : L0 rec writes slots [8s,8s+8)&15, L1 coop reads [8s-8,8s)&15
// ===========================================================================
__global__ __launch_bounds__(512, 2)
void lstm_hy(const float* __restrict__ x,         // [B][T][64] fp32
             const float* __restrict__ w_ih0,     // [256][64]
             const float* __restrict__ w_hh0,     // [256][64]
             const float* __restrict__ b_ih0,     // [256]
             const float* __restrict__ b_hh0,     // [256]
             const float* __restrict__ w_ih1,     // [256][64]
             const float* __restrict__ w_hh1,     // [256][64]
             const float* __restrict__ b_ih1,     // [256]
             const float* __restrict__ b_hh1,     // [256]
             const float* __restrict__ fc_w,      // [32][64]
             const float* __restrict__ fc_b,      // [32]
             float* __restrict__ out)             // [B][32]
{
    // pre rings: [buf][tau][row][unit][gate] f32 (scaled; bias added in rec)
    __shared__ float  pre0[2][SS][4][64][4];      // 64 KB
    __shared__ float  pre1[2][SS][4][64][4];      // 64 KB
    // h rings: [slot][row][64] bf16; within-row byte ^= 16*row swizzle
    __shared__ ushort h0r[16][4][64];             // 8 KB
    __shared__ ushort h1r[2][4][64];              // 1 KB

    const int tid  = threadIdx.x;
    const int wv   = tid >> 6;            // 0..7
    const bool L1w = (wv >= 4);           // layer-1 wave
    const int r    = wv & 3;              // this wave's batch row (= c-block)
    const int ln   = tid & 63;
    const int ll   = ln & 15;
    const int lq   = ln >> 4;
    const int b0   = blockIdx.x * MM;
    const int hu   = 16 * lq + ll;        // the ONE cell unit this lane owns
    const int hsw  = 16 * r;              // h-ring row swizzle
    const int myrow = r;
    const f32x4 z4 = (f32x4){0.f, 0.f, 0.f, 0.f};

    // ---- W_hh of this wave's layer: 32 B-frags (128 VGPR), scales folded
    const float* whh = L1w ? w_hh1 : w_hh0;
    short8 bf[4][4][2];
#pragma unroll
    for (int g = 0; g < 4; ++g) {
        const float sc = (g == 2) ? K2 : -LOG2E;
#pragma unroll
        for (int c = 0; c < 4; ++c) {
            const int col = 64 * g + 16 * c + ll;
#pragma unroll
            for (int kt = 0; kt < 2; ++kt) {
                const float* src = whh + col * 64 + 32 * kt + 8 * lq;
                const float4 v0 = *(const float4*)src;
                const float4 v1 = *(const float4*)(src + 4);
                short8 b;
                b[0] = (short)f2bf(v0.x * sc); b[1] = (short)f2bf(v0.y * sc);
                b[2] = (short)f2bf(v0.z * sc); b[3] = (short)f2bf(v0.w * sc);
                b[4] = (short)f2bf(v1.x * sc); b[5] = (short)f2bf(v1.y * sc);
                b[6] = (short)f2bf(v1.z * sc); b[7] = (short)f2bf(v1.w * sc);
                bf[g][c][kt] = b;
            }
        }
    }

    // ---- coop W_ih tiles (g=0..3, c=r) of this wave's layer (32 VGPR)
    const float* wih = L1w ? w_ih1 : w_ih0;
    short8 wi[4][2];
#pragma unroll
    for (int g = 0; g < 4; ++g) {
        const float sc = (g == 2) ? K2 : -LOG2E;
        const int col = 64 * g + 16 * r + ll;
#pragma unroll
        for (int kt = 0; kt < 2; ++kt) {
            const float* src = wih + col * 64 + 32 * kt + 8 * lq;
            const float4 v0 = *(const float4*)src;
            const float4 v1 = *(const float4*)(src + 4);
            short8 b;
            b[0] = (short)f2bf(v0.x * sc); b[1] = (short)f2bf(v0.y * sc);
            b[2] = (short)f2bf(v0.z * sc); b[3] = (short)f2bf(v0.w * sc);
            b[4] = (short)f2bf(v1.x * sc); b[5] = (short)f2bf(v1.y * sc);
            b[6] = (short)f2bf(v1.z * sc); b[7] = (short)f2bf(v1.w * sc);
            wi[g][kt] = b;
        }
    }

    // ---- bias for THIS lane's unit (added at rec time, scaled)
    const float* bih = L1w ? b_ih1 : b_ih0;
    const float* bhh = L1w ? b_hh1 : b_hh0;
    const float bR0 = (bih[0   + hu] + bhh[0   + hu]) * -LOG2E;
    const float bR1 = (bih[64  + hu] + bhh[64  + hu]) * -LOG2E;
    const float bR2 = (bih[128 + hu] + bhh[128 + hu]) *  K2;
    const float bR3 = (bih[192 + hu] + bhh[192 + hu]) * -LOG2E;

    // zero h rings (h(-1) = c(-1) = 0)
    for (int i = tid; i < 16 * 4 * 64; i += 512) ((ushort*)h0r)[i] = 0;
    for (int i = tid; i < 2 * 4 * 64;  i += 512) ((ushort*)h1r)[i] = 0;

    // coop A-pack helpers: A row m = ll -> (tau = ll>>2, row = ll&3)
    const int xrowc = ll & 3, xtauc = ll >> 2;
    const size_t xbase = ((size_t)(b0 + xrowc) * TT) * 64 + 8 * lq;

    float cc = 0.f;                       // this lane's single cell state

// coop tile-set: D = A@W + 0, scatter acc[ri] -> [tau=4hh+lq][row=ri][u][g]
#define COOPMM(PRE, BUF, A0_, A1_)                                            \
    _Pragma("unroll")                                                         \
    for (int g = 0; g < 4; ++g) {                                             \
        f32x4 acc = MFMA(A1_, wi[g][1], MFMA(A0_, wi[g][0], z4, 0,0,0), 0,0,0); \
        float* dd = &PRE[BUF][4 * hh + lq][0][16 * r + ll][g];                \
        dd[0] = acc[0]; dd[256] = acc[1]; dd[512] = acc[2]; dd[768] = acc[3]; \
    }

// one slot of recurrence: 8 steps, barrier-free (same-wave in-order LDS)
#define RECSLOT(RING, SLOTMASK, PRE, U_)                                      \
    {                                                                         \
        const int t0_ = SS * (U_);                                            \
        const char* prb = (const char*)&PRE[(U_) & 1][0][myrow][hu][0];       \
        _Pragma("unroll")                                                     \
        for (int tau = 0; tau < SS; ++tau) {                                  \
            const int t = t0_ + tau;                                          \
            const f32x4 y4 = *(const f32x4*)(prb + tau * 4096);               \
            const char* hb = (const char*)(RING)                              \
                             + ((t - 1) & (SLOTMASK)) * 512 + myrow * 128;    \
            const short8 a0 = *(const short8*)(hb + ((16 * lq) ^ hsw));       \
            const short8 a1 = *(const short8*)(hb + ((64 + 16 * lq) ^ hsw));  \
            float y0 = y4[0] + bR0, y1 = y4[1] + bR1;                         \
            float y2 = y4[2] + bR2, y3 = y4[3] + bR3;                         \
            _Pragma("unroll")                                                 \
            for (int c = 0; c < 4; ++c) {                                     \
                f32x4 f0 = MFMA(a0, bf[0][c][0], z4, 0, 0, 0);                \
                f32x4 f1 = MFMA(a0, bf[1][c][0], z4, 0, 0, 0);                \
                f32x4 f2 = MFMA(a0, bf[2][c][0], z4, 0, 0, 0);                \
                f32x4 f3 = MFMA(a0, bf[3][c][0], z4, 0, 0, 0);                \
                f0 = MFMA(a1, bf[0][c][1], f0, 0, 0, 0);                      \
                f1 = MFMA(a1, bf[1][c][1], f1, 0, 0, 0);                      \
                f2 = MFMA(a1, bf[2][c][1], f2, 0, 0, 0);                      \
                f3 = MFMA(a1, bf[3][c][1], f3, 0, 0, 0);                      \
                if (lq == c) { y0 += f0[0]; y1 += f1[0];                      \
                               y2 += f2[0]; y3 += f3[0]; }                    \
            }                                                                 \
            const float Ef = exp2f_(y1);                                      \
            const float Ei = exp2f_(y0);                                      \
            const float Eg = exp2f_(fminf(y2, 80.f));                         \
            const float sf = __builtin_amdgcn_rcpf(1.f + Ef);                 \
            const float rd = __builtin_amdgcn_rcpf((1.f + Ei) * (1.f + Eg));  \
            cc = sf * cc + (Eg - 1.f) * rd;                                   \
            const float Ec = exp2f_(fminf(cc * K2, 80.f));                    \
            const float Eo = exp2f_(y3);                                      \
            const float r2 = __builtin_amdgcn_rcpf((1.f + Eo) * (1.f + Ec));  \
            union { float f; unsigned u; } hv_; hv_.f = (Ec - 1.f) * r2;      \
            *(ushort*)((char*)(RING) + (t & (SLOTMASK)) * 512 + myrow * 128   \
                       + ((2 * hu) ^ hsw)) = (ushort)((hv_.u + 0x8000u) >> 16); \
        }                                                                     \
    }

    // ---- prologue: pre0 for slot 0 (L0 waves); visible at first BAR
    if (!L1w) {
#pragma unroll
        for (int hh = 0; hh < 2; ++hh) {
            const float* px = x + xbase + (size_t)(4 * hh + xtauc) * 64;
            const float4 v0 = *(const float4*)px;
            const float4 v1 = *(const float4*)(px + 4);
            const float4 v2 = *(const float4*)(px + 32);
            const float4 v3 = *(const float4*)(px + 36);
            const short8 a0 = pack8(v0, v1), a1 = pack8(v2, v3);
            COOPMM(pre0, 0, a0, a1)
        }
    }

    for (int s = 0; s < NSLOT; ++s) {
        BAR();
        // -- issue coop inputs EARLY (latency hides under the 8 rec steps)
        float4 xv[2][4];
        short8 hA[2][2];
        if (!L1w) {
            if (s < 63) {
                const int t0n = SS * (s + 1);
#pragma unroll
                for (int hh = 0; hh < 2; ++hh) {
                    const float* px = x + xbase + (size_t)(t0n + 4 * hh + xtauc) * 64;
                    xv[hh][0] = *(const float4*)px;
                    xv[hh][1] = *(const float4*)(px + 4);
                    xv[hh][2] = *(const float4*)(px + 32);
                    xv[hh][3] = *(const float4*)(px + 36);
                }
            }
        } else {
            if (s >= 1 && s <= 64) {
                const int t1 = SS * (s - 1);
#pragma unroll
                for (int hh = 0; hh < 2; ++hh) {
                    const int tt = t1 + 4 * hh + xtauc;
                    const char* hp = (const char*)h0r + (tt & 15) * 512 + xrowc * 128;
                    hA[hh][0] = *(const short8*)(hp + ((16 * lq) ^ (16 * xrowc)));
                    hA[hh][1] = *(const short8*)(hp + ((64 + 16 * lq) ^ (16 * xrowc)));
                }
            }
        }
        // -- recurrence (8 steps, intra-wave)
        if (!L1w) { if (s < 64) RECSLOT(h0r, 15, pre0, s) }
        else      { if (s >= 2) RECSLOT(h1r, 1,  pre1, s - 2) }
        // -- coop compute (inputs arrived during rec)
        if (!L1w) {
            if (s < 63) {
#pragma unroll
                for (int hh = 0; hh < 2; ++hh) {
                    const short8 a0 = pack8(xv[hh][0], xv[hh][1]);
                    const short8 a1 = pack8(xv[hh][2], xv[hh][3]);
                    COOPMM(pre0, (s + 1) & 1, a0, a1)
                }
            }
        } else {
            if (s >= 1 && s <= 64) {
#pragma unroll
                for (int hh = 0; hh < 2; ++hh)
                    COOPMM(pre1, (s - 1) & 1, hA[hh][0], hA[hh][1])
            }
        }
    }
#undef RECSLOT
#undef COOPMM

    BAR();
    // FC + softplus on h1(511) = h1r slot 1 (row-swizzled); 128 outputs
    if (tid < MM * OO) {
        const int row = tid >> 5, o = tid & 31;
        float a = fc_b[o];
#pragma unroll
        for (int j = 0; j < 64; ++j) {
            const ushort hv = *(const ushort*)((const char*)h1r + 512
                              + row * 128 + ((2 * j) ^ (16 * row)));
            a = fmaf(fc_w[o * 64 + j], bf2f(hv), a);
        }
        out[(size_t)(b0 + row) * OO + o] =
            fmaxf(a, 0.0f) + log1pf(__expf(-fabsf(a)));   // stable softplus
    }
}

extern "C" void kernel_launch(void* const* d_in, const int* in_sizes, int n_in,
                              void* d_out, int out_size, void* d_ws, size_t ws_size,
                              hipStream_t stream) {
    const float* x     = (const float*)d_in[0];
    const float* w_ih0 = (const float*)d_in[1];
    const float* w_hh0 = (const float*)d_in[2];
    const float* b_ih0 = (const float*)d_in[3];
    const float* b_hh0 = (const float*)d_in[4];
    const float* w_ih1 = (const float*)d_in[5];
    const float* w_hh1 = (const float*)d_in[6];
    const float* b_ih1 = (const float*)d_in[7];
    const float* b_hh1 = (const float*)d_in[8];
    const float* fc_w  = (const float*)d_in[9];
    const float* fc_b  = (const float*)d_in[10];
    float* out = (float*)d_out;

    lstm_hy<<<dim3(NBLK), dim3(512), 0, stream>>>(
        x, w_ih0, w_hh0, b_ih0, b_hh0,
        w_ih1, w_hh1, b_ih1, b_hh1, fc_w, fc_b, out);
}

// Round 6
// 569.477 us; speedup vs baseline: 1.2101x; 1.2101x over previous
//
#include <hip/hip_runtime.h>
#include <math.h>

// (B,T,D,H,O) = (1024, 512, 64, 64, 32)
#define BB 1024
#define TT 512
#define OO 32
#define MM 4               // batch rows per block
#define NBLK (BB/MM)       // 256 blocks -> all 256 CUs
#define SS 8               // timesteps per slot
#define NSLOT 66           // L0 rec s=0..63, L1 rec s=2..65

typedef __attribute__((ext_vector_type(8))) short short8;   // 8 bf16
typedef __attribute__((ext_vector_type(4))) float f32x4;    // MFMA C/D

#define MFMA __builtin_amdgcn_mfma_f32_16x16x32_bf16
#define LOG2E 1.4426950408889634f
#define K2    2.8853900817779268f   /* 2*log2(e) */

// step barrier (LDS only) and slot barrier (also drains global_load_lds DMA
// so OTHER waves may read the staged x after the rendezvous)
#define BAR()  asm volatile("s_waitcnt lgkmcnt(0)\n\ts_barrier" ::: "memory")
#define BARV() asm volatile("s_waitcnt vmcnt(0) lgkmcnt(0)\n\ts_barrier" ::: "memory")

__device__ __forceinline__ float exp2f_(float x) {
#if __has_builtin(__builtin_amdgcn_exp2f)
    return __builtin_amdgcn_exp2f(x);
#else
    float r; asm("v_exp_f32 %0, %1" : "=v"(r) : "v"(x)); return r;
#endif
}

// fp32 -> bf16 RNE (one-time weight conversion)
__device__ __forceinline__ ushort f2bf(float f) {
    union { float f; unsigned u; } v; v.f = f;
    unsigned r = v.u + 0x7FFF + ((v.u >> 16) & 1);
    return (ushort)(r >> 16);
}
__device__ __forceinline__ float bf2f(ushort u) {
    union { unsigned u; float f; } v; v.u = ((unsigned)u) << 16; return v.f;
}
// pack two fp32 -> bf16x2 via v_perm (round-half-up)
__device__ __forceinline__ unsigned pkbf(float a, float b) {
    union { float f; unsigned u; } x, y; x.f = a; y.f = b;
    return __builtin_amdgcn_perm(y.u + 0x8000u, x.u + 0x8000u, 0x07060302u);
}
__device__ __forceinline__ short8 pack8(const float4& a, const float4& b) {
    union { unsigned u[4]; short8 s; } r;
    r.u[0] = pkbf(a.x, a.y); r.u[1] = pkbf(a.z, a.w);
    r.u[2] = pkbf(b.x, b.y); r.u[3] = pkbf(b.z, b.w);
    return r.s;
}

// async global->LDS, 16B per lane (dst = wave-uniform base + lane*16)
__device__ __forceinline__ void gll16(const float* g, void* l) {
    __builtin_amdgcn_global_load_lds(
        (const __attribute__((address_space(1))) void*)g,
        (__attribute__((address_space(3))) void*)l, 16, 0, 0);
}

// ===========================================================================
// Thin-wave LSTM. 4 waves / 256 thr / block, 256 blocks, 1 wave/SIMD with the
// full 512-VGPR budget (the 2-waves/SIMD + MFMA combo caps arch VGPRs at 128
// and spilled in R2/R4 -- avoided by design here).
//   wv0 = L0 units 0-31, wv1 = L0 units 32-63 (W_hh0 half each, 64 VGPR)
//   wv2 = L1 units 0-31, wv3 = L1 units 32-63 (W_hh1 half each)
// M-pack: batch row r at M-row 4r (A row m <- h row m>>2) -> lane (q,l) reg0
// of tile (g,c) = batch row q, unit 16c+l. Wave owns c in {cA, cA+1} -> each
// lane runs TWO cells (units 16cA+l, 16cA+16+l of row q): 16 MFMA as 8
// independent 2-chains + 16 trans per step. Cross-wave h-half exchange ->
// per-step block barrier (cheap: R1 vs R3 showed ~100cy).
//
// The x@W_ih0 / h0@W_ih1 MFMAs are OUT of the recurrence: coop chunks spread
// over the 8 steps of each slot (independent work that fills rec latency
// bubbles). Coop tile ownership: wave wv owns gate g=wv, all 4 c-blocks,
// for BOTH pre0 (W_ih0) and pre1 (W_ih1). x staged via global_load_lds
// issued one slot ahead; slot-boundary BARV() drains DMA for all waves.
//
// pre layout [buf][tau][unit][rowX][gate] f32: rec read = 1 b128/cell
// (conflict-free); coop scatter writes XOR the row field with (tau&3) to
// spread banks (bijective, applied identically on read).
// LDS budget (<= 160 KiB): pre0 64K + pre1 64K + h0 8K + h1 1K + xs 16K
//   = 156672 B (R5 failed compile at 161 KB with a 32-deep h0 ring; 16-deep
//   preserves the same disjointness: writes [8s,8s+8), coop reads [8s-8,8s)
//   are opposite halves of a 16-ring).
// Rings/parity per slot s:
//   pre0: L0 reads buf s&1;  coop writes buf (s+1)&1 (for slot s+1)
//   pre1: L1 reads buf s&1 (= (s-2)&1); coop writes buf (s-1)&1
//   h0:   16-deep; L0 writes [8s,8s+8)&15, coop pre1 reads [8s-8,8s)&15
//   x:    xbuf[(s+2)&1] staged at slot s, read by coop at slot s+1
// ===========================================================================
__global__ __launch_bounds__(256, 1)
void lstm_tw(const float* __restrict__ x,         // [B][T][64] fp32
             const float* __restrict__ w_ih0,     // [256][64]
             const float* __restrict__ w_hh0,     // [256][64]
             const float* __restrict__ b_ih0,     // [256]
             const float* __restrict__ b_hh0,     // [256]
             const float* __restrict__ w_ih1,     // [256][64]
             const float* __restrict__ w_hh1,     // [256][64]
             const float* __restrict__ b_ih1,     // [256]
             const float* __restrict__ b_hh1,     // [256]
             const float* __restrict__ fc_w,      // [32][64]
             const float* __restrict__ fc_b,      // [32]
             float* __restrict__ out)             // [B][32]
{
    __shared__ __align__(16) float  pre0s[2][SS][64][4][4];   // 64 KB
    __shared__ __align__(16) float  pre1s[2][SS][64][4][4];   // 64 KB
    __shared__ __align__(16) ushort h0s[16][4][64];           // 8 KB
    __shared__ __align__(16) ushort h1s[2][4][64];            // 1 KB
    __shared__ __align__(16) float  xs[2][4][SS][64];         // 16 KB

    const int tid = threadIdx.x;
    const int wv  = tid >> 6;            // 0..3
    const int lay = wv >> 1;             // 0: layer-0 waves, 1: layer-1
    const int cA  = 2 * (wv & 1);        // owned c-pair {cA, cA+1}
    const int ln  = tid & 63;
    const int l   = ln & 15;
    const int q   = ln >> 4;
    const int b0  = blockIdx.x * MM;
    const f32x4 z4 = (f32x4){0.f, 0.f, 0.f, 0.f};

    // ---- rec weights: W_hh half (8 tiles x 2 kt = 16 short8 = 64 VGPR)
    const float* whh = lay ? w_hh1 : w_hh0;
    short8 bf[4][2][2];                  // [g][ci][kt]
#pragma unroll
    for (int g = 0; g < 4; ++g) {
        const float sc = (g == 2) ? K2 : -LOG2E;
#pragma unroll
        for (int ci = 0; ci < 2; ++ci) {
            const int col = 64 * g + 16 * (cA + ci) + l;
#pragma unroll
            for (int kt = 0; kt < 2; ++kt) {
                const float* src = whh + col * 64 + 32 * kt + 8 * q;
                const float4 v0 = *(const float4*)src;
                const float4 v1 = *(const float4*)(src + 4);
                short8 b;
                b[0] = (short)f2bf(v0.x * sc); b[1] = (short)f2bf(v0.y * sc);
                b[2] = (short)f2bf(v0.z * sc); b[3] = (short)f2bf(v0.w * sc);
                b[4] = (short)f2bf(v1.x * sc); b[5] = (short)f2bf(v1.y * sc);
                b[6] = (short)f2bf(v1.z * sc); b[7] = (short)f2bf(v1.w * sc);
                bf[g][ci][kt] = b;
            }
        }
    }

    // ---- coop weights: gate g=wv, c=j, for W_ih0 AND W_ih1 (64 VGPR)
    const float scw = (wv == 2) ? K2 : -LOG2E;
    short8 wi0[4][2], wi1[4][2];
    float  bv0[4], bv1[4];
#pragma unroll
    for (int j = 0; j < 4; ++j) {
        const int col = 64 * wv + 16 * j + l;
        bv0[j] = (b_ih0[col] + b_hh0[col]) * scw;
        bv1[j] = (b_ih1[col] + b_hh1[col]) * scw;
#pragma unroll
        for (int kt = 0; kt < 2; ++kt) {
            const int ko = 32 * kt + 8 * q;
#define LDW(dst, W)                                                           \
            { const float4 v0 = *(const float4*)(W + col * 64 + ko);          \
              const float4 v1 = *(const float4*)(W + col * 64 + ko + 4);      \
              short8 b;                                                       \
              b[0]=(short)f2bf(v0.x*scw); b[1]=(short)f2bf(v0.y*scw);         \
              b[2]=(short)f2bf(v0.z*scw); b[3]=(short)f2bf(v0.w*scw);         \
              b[4]=(short)f2bf(v1.x*scw); b[5]=(short)f2bf(v1.y*scw);         \
              b[6]=(short)f2bf(v1.z*scw); b[7]=(short)f2bf(v1.w*scw);         \
              dst = b; }
            LDW(wi0[j][kt], w_ih0)
            LDW(wi1[j][kt], w_ih1)
#undef LDW
        }
    }

    // ---- zero h rings
    for (int i = tid; i < 16 * 4 * 64; i += 256) ((ushort*)h0s)[i] = 0;
    for (int i = tid; i < 2 * 4 * 64;  i += 256) ((ushort*)h1s)[i] = 0;

    // ---- prologue: stage xchunk(0)->xs[0], xchunk(1)->xs[1]
#pragma unroll
    for (int c = 0; c < 2; ++c)
#pragma unroll
        for (int k = 0; k < 2; ++k) {
            const int th = 4 * k;
            const float* sr = x + (((size_t)(b0 + wv) * TT + 8 * c + th + (ln >> 4)) * 64
                                   + (ln & 15) * 4);
            gll16(sr, (char*)xs + c * 8192 + wv * 2048 + th * 256);
        }
    BARV();
    // compute pre0[0] (slot 0) from xs[0]
    {
#pragma unroll
        for (int mt = 0; mt < 2; ++mt) {
            const float* xp = (const float*)xs + (l & 3) * 512
                              + ((l >> 2) + 4 * mt) * 64 + 8 * q;
            const float4 v0 = *(const float4*)xp;
            const float4 v1 = *(const float4*)(xp + 4);
            const float4 v2 = *(const float4*)(xp + 32);
            const float4 v3 = *(const float4*)(xp + 36);
            const short8 xa0 = pack8(v0, v1);
            const short8 xa1 = pack8(v2, v3);
            char* wp = (char*)pre0s + (q + 4 * mt) * 4096;
#pragma unroll
            for (int j = 0; j < 4; ++j) {
                f32x4 a = (f32x4){bv0[j], bv0[j], bv0[j], bv0[j]};
                a = MFMA(xa0, wi0[j][0], a, 0, 0, 0);
                a = MFMA(xa1, wi0[j][1], a, 0, 0, 0);
                char* wpp = wp + (16 * j + l) * 64 + wv * 4;
#pragma unroll
                for (int ri = 0; ri < 4; ++ri)
                    *(float*)(wpp + ((ri * 16) ^ (q << 4))) = a[ri];
            }
        }
    }
    BAR();

    float cc0 = 0.f, cc1 = 0.f;          // this lane's two cell states

#define CELL(CCV, Y0, Y1, Y2, Y3, HVAL)                                       \
    {                                                                         \
        const float Ef = exp2f_(Y1);                                          \
        const float Ei = exp2f_(Y0);                                          \
        const float Eg = exp2f_(fminf((Y2), 80.f));                           \
        const float sf = __builtin_amdgcn_rcpf(1.f + Ef);                     \
        const float rd = __builtin_amdgcn_rcpf((1.f + Ei) * (1.f + Eg));      \
        CCV = sf * CCV + (Eg - 1.f) * rd;                                     \
        const float Ec = exp2f_(fminf(CCV * K2, 80.f));                       \
        const float Eo = exp2f_(Y3);                                          \
        const float r2 = __builtin_amdgcn_rcpf((1.f + Eo) * (1.f + Ec));      \
        union { float f; unsigned u; } hv_; hv_.f = (Ec - 1.f) * r2;          \
        HVAL = (ushort)((hv_.u + 0x8000u) >> 16);                             \
    }

    for (int s = 0; s < NSLOT; ++s) {
        const int pb   = s & 1;                 // rec read buf (pre0 and pre1)
        const bool doA = (lay == 0) && (s < 64);
        const bool doB = (lay == 1) && (s >= 2);
        const bool cp0 = (s <= 62);             // coop pre0 for slot s+1
        const bool cp1 = (s >= 1 && s <= 64);   // coop pre1 for L1-slot s-1
        const int t0   = doA ? (8 * s) : (8 * (s - 2));
        const int t1C  = 8 * (s - 1);           // coop pre1 h0 t' base
        short8 ca0 = {0,0,0,0,0,0,0,0}, ca1 = {0,0,0,0,0,0,0,0};

#pragma unroll
        for (int tau = 0; tau < SS; ++tau) {
            if (tau == 0) { BARV(); } else { BAR(); }

            // ---- rec loads (chain-critical: issue first)
            short8 a0, a1; f32x4 pv0, pv1;
            if (doA || doB) {
                const int t  = t0 + tau;
                const int hm = doA ? 15 : 1;
                const int r  = l >> 2;
                const char* hb = (doA ? (const char*)h0s : (const char*)h1s)
                                 + ((t - 1) & hm) * 512 + r * 128;
                a0 = *(const short8*)(hb + ((16 * q) ^ (r << 4)));
                a1 = *(const short8*)(hb + ((64 + 16 * q) ^ (r << 4)));
                const char* pr = (doA ? (const char*)pre0s : (const char*)pre1s)
                                 + pb * 16384 + tau * 4096
                                 + ((16 * q) ^ ((tau & 3) << 4));
                pv0 = *(const f32x4*)(pr + (16 * cA + l) * 64);
                pv1 = *(const f32x4*)(pr + (16 * cA + 16 + l) * 64);
            }

            // ---- coop: x staging for slot s+2 (issued here, drained at the
            // NEXT slot's BARV before anyone reads it)
            if (tau == 0 && s <= 61) {
                const int sg = s + 2;
                char* xd = (char*)xs + (sg & 1) * 8192 + wv * 2048;
#pragma unroll
                for (int k = 0; k < 2; ++k) {
                    const int th = 4 * k;
                    const float* sr = x + (((size_t)(b0 + wv) * TT + 8 * sg + th
                                            + (ln >> 4)) * 64 + (ln & 15) * 4);
                    gll16(sr, xd + th * 256);
                }
            }

            // ---- coop chunks (independent filler work)
            if (tau < 4) {
                if (cp0) {                       // pre0 for slot s+1
                    const int mt = tau >> 1;
                    if ((tau & 1) == 0) {
                        const float* xp = (const float*)xs + (pb ^ 1) * 2048
                                          + (l & 3) * 512
                                          + ((l >> 2) + 4 * mt) * 64 + 8 * q;
                        const float4 v0 = *(const float4*)xp;
                        const float4 v1 = *(const float4*)(xp + 4);
                        const float4 v2 = *(const float4*)(xp + 32);
                        const float4 v3 = *(const float4*)(xp + 36);
                        ca0 = pack8(v0, v1); ca1 = pack8(v2, v3);
                    }
                    const int j0 = 2 * (tau & 1);
                    char* wp = (char*)pre0s + (pb ^ 1) * 16384 + (q + 4 * mt) * 4096;
#pragma unroll
                    for (int jj = 0; jj < 2; ++jj) {
                        const int j = j0 + jj;
                        f32x4 a = (f32x4){bv0[j], bv0[j], bv0[j], bv0[j]};
                        a = MFMA(ca0, wi0[j][0], a, 0, 0, 0);
                        a = MFMA(ca1, wi0[j][1], a, 0, 0, 0);
                        char* wpp = wp + (16 * j + l) * 64 + wv * 4;
#pragma unroll
                        for (int ri = 0; ri < 4; ++ri)
                            *(float*)(wpp + ((ri * 16) ^ (q << 4))) = a[ri];
                    }
                }
            } else {
                if (cp1) {                       // pre1 for L1-slot s-1
                    const int mt = (tau - 4) >> 1;
                    if ((tau & 1) == 0) {
                        const int tt = t1C + (l >> 2) + 4 * mt;
                        const int rr = l & 3;
                        const char* hp = (const char*)h0s + (tt & 15) * 512 + rr * 128;
                        ca0 = *(const short8*)(hp + ((16 * q) ^ (rr << 4)));
                        ca1 = *(const short8*)(hp + ((64 + 16 * q) ^ (rr << 4)));
                    }
                    const int j0 = 2 * (tau & 1);
                    char* wp = (char*)pre1s + (pb ^ 1) * 16384 + (q + 4 * mt) * 4096;
#pragma unroll
                    for (int jj = 0; jj < 2; ++jj) {
                        const int j = j0 + jj;
                        f32x4 a = (f32x4){bv1[j], bv1[j], bv1[j], bv1[j]};
                        a = MFMA(ca0, wi1[j][0], a, 0, 0, 0);
                        a = MFMA(ca1, wi1[j][1], a, 0, 0, 0);
                        char* wpp = wp + (16 * j + l) * 64 + wv * 4;
#pragma unroll
                        for (int ri = 0; ri < 4; ++ri)
                            *(float*)(wpp + ((ri * 16) ^ (q << 4))) = a[ri];
                    }
                }
            }

            // ---- rec compute: 8 independent 2-chains, 2 cells/lane
            if (doA || doB) {
                f32x4 acc[2][4];
#pragma unroll
                for (int ci = 0; ci < 2; ++ci)
#pragma unroll
                    for (int g = 0; g < 4; ++g)
                        acc[ci][g] = MFMA(a0, bf[g][ci][0], z4, 0, 0, 0);
#pragma unroll
                for (int ci = 0; ci < 2; ++ci)
#pragma unroll
                    for (int g = 0; g < 4; ++g)
                        acc[ci][g] = MFMA(a1, bf[g][ci][1], acc[ci][g], 0, 0, 0);

                const int t  = t0 + tau;
                const int hm = doA ? 15 : 1;
                char* hw = (doA ? (char*)h0s : (char*)h1s)
                           + (t & hm) * 512 + q * 128;
                {
                    const float y0 = pv0[0] + acc[0][0][0];
                    const float y1 = pv0[1] + acc[0][1][0];
                    const float y2 = pv0[2] + acc[0][2][0];
                    const float y3 = pv0[3] + acc[0][3][0];
                    ushort hval; CELL(cc0, y0, y1, y2, y3, hval)
                    *(ushort*)(hw + ((2 * (16 * cA + l)) ^ (q << 4))) = hval;
                }
                {
                    const float y0 = pv1[0] + acc[1][0][0];
                    const float y1 = pv1[1] + acc[1][1][0];
                    const float y2 = pv1[2] + acc[1][2][0];
                    const float y3 = pv1[3] + acc[1][3][0];
                    ushort hval; CELL(cc1, y0, y1, y2, y3, hval)
                    *(ushort*)(hw + ((2 * (16 * cA + 16 + l)) ^ (q << 4))) = hval;
                }
            }
        }
    }
#undef CELL

    BAR();
    // FC + softplus on h1(511) = h1s slot 1 (row-swizzled); 128 outputs
    if (tid < MM * OO) {
        const int row = tid >> 5, o = tid & 31;
        float a = fc_b[o];
#pragma unroll
        for (int j = 0; j < 64; ++j) {
            const ushort hv = *(const ushort*)((const char*)h1s + 512
                              + row * 128 + ((2 * j) ^ (row << 4)));
            a = fmaf(fc_w[o * 64 + j], bf2f(hv), a);
        }
        out[(size_t)(b0 + row) * OO + o] =
            fmaxf(a, 0.0f) + log1pf(__expf(-fabsf(a)));   // stable softplus
    }
}

extern "C" void kernel_launch(void* const* d_in, const int* in_sizes, int n_in,
                              void* d_out, int out_size, void* d_ws, size_t ws_size,
                              hipStream_t stream) {
    const float* x     = (const float*)d_in[0];
    const float* w_ih0 = (const float*)d_in[1];
    const float* w_hh0 = (const float*)d_in[2];
    const float* b_ih0 = (const float*)d_in[3];
    const float* b_hh0 = (const float*)d_in[4];
    const float* w_ih1 = (const float*)d_in[5];
    const float* w_hh1 = (const float*)d_in[6];
    const float* b_ih1 = (const float*)d_in[7];
    const float* b_hh1 = (const float*)d_in[8];
    const float* fc_w  = (const float*)d_in[9];
    const float* fc_b  = (const float*)d_in[10];
    float* out = (float*)d_out;

    lstm_tw<<<dim3(NBLK), dim3(256), 0, stream>>>(
        x, w_ih0, w_hh0, b_ih0, b_hh0,
        w_ih1, w_hh1, b_ih1, b_hh1, fc_w, fc_b, out);
}